// Round 6
// baseline (104.875 us; speedup 1.0000x reference)
//
#include <hip/hip_runtime.h>
#include <hip/hip_bf16.h>

// Problem constants
#define BB 2
#define SS 2048
#define DD 1024
#define HH 16
#define MMR (BB*SS)   // 4096 rows
#define ND3 3072      // fused QKV width

typedef __hip_bfloat16 bf;
typedef __bf16 bf16x8 __attribute__((ext_vector_type(8)));
typedef float f32x4 __attribute__((ext_vector_type(4)));
typedef float f32x16 __attribute__((ext_vector_type(16)));

#define VMCNT(n) asm volatile("s_waitcnt vmcnt(" #n ")" ::: "memory")

__device__ __forceinline__ f32x4 mfma16(bf16x8 a, bf16x8 b, f32x4 c) {
    return __builtin_amdgcn_mfma_f32_16x16x32_bf16(a, b, c, 0, 0, 0);
}
__device__ __forceinline__ f32x16 mfma32(bf16x8 a, bf16x8 b, f32x16 c) {
    return __builtin_amdgcn_mfma_f32_32x32x16_bf16(a, b, c, 0, 0, 0);
}
__device__ __forceinline__ unsigned cvt_pk_bf16(float lo, float hi) {
    unsigned r;
    asm("v_cvt_pk_bf16_f32 %0, %1, %2" : "=v"(r) : "v"(lo), "v"(hi));
    return r;
}
// after: a = {a.lo31, b.lo31}, b = {a.hi31, b.hi31}
__device__ __forceinline__ void pl32swap(unsigned& a, unsigned& b) {
    asm("v_permlane32_swap_b32 %0, %1" : "+v"(a), "+v"(b));
}
// async global->LDS, 16B/lane; LDS dest = wave-uniform base + lane*16
__device__ __forceinline__ void glds16(const bf* g, bf* l) {
    __builtin_amdgcn_global_load_lds(
        (const __attribute__((address_space(1))) void*)g,
        (__attribute__((address_space(3))) void*)l,
        16, 0, 0);
}

// ---------------------------------------------------------------
// All f32->bf16 converts in ONE launch. blocks 0..4095: X (4M elems);
// blocks 4096..8191: Wq,Wk,Wv (into Wqkv) and Wo (into Wob), 1M each.
__global__ __launch_bounds__(256) void k_convert(const float* __restrict__ X,
                                                 const float* __restrict__ Wq,
                                                 const float* __restrict__ Wk,
                                                 const float* __restrict__ Wv,
                                                 const float* __restrict__ Wo,
                                                 bf* __restrict__ Xb,
                                                 bf* __restrict__ Wqkv,
                                                 bf* __restrict__ Wob) {
    const int bid = blockIdx.x;
    const float* src;
    bf* dst;
    int off;
    if (bid < 4096) {
        src = X; dst = Xb; off = bid;
    } else {
        const int r = (bid - 4096) >> 10;
        src = (r == 0) ? Wq : (r == 1) ? Wk : (r == 2) ? Wv : Wo;
        dst = (r < 3) ? (Wqkv + (size_t)r * 1048576) : Wob;
        off = (bid - 4096) & 1023;
    }
    const int j = (off * 256 + threadIdx.x) * 4;
    float4 v = *(const float4*)(src + j);
    bf tmp[4];
    tmp[0] = __float2bfloat16(v.x);
    tmp[1] = __float2bfloat16(v.y);
    tmp[2] = __float2bfloat16(v.z);
    tmp[3] = __float2bfloat16(v.w);
    *(uint2*)(dst + j) = *(const uint2*)tmp;
}

// ---------------------------------------------------------------
// BMxBN-tile GEMM, BK=32, 4 waves. 3-buffer LDS pipeline, counted vmcnt,
// raw s_barrier (loads in flight across barrier), setprio'd MFMA cluster.
// LDS seg-XOR swizzle (seg' = seg ^ ((row>>1)&3)): fragment ds_read_b128
// goes from 8-way bank conflict to 2-way (free). Both-sides: pre-swizzled
// glds SOURCE + swizzled READ; LDS dest stays linear.
// MODE 0: C = A@Bt^T -> float out.
// MODE 1 (BM=128): fused QKV epilogue: cols<2048 -> per-head L2-norm * mask ->
//   Qn/Kn [B*H,S,64]; cols>=2048 -> TRANSPOSED bf16 write to Vt [B*H,64,S].
template<int MODE, int BM, int BN>
__global__ __launch_bounds__(256) void k_gemm(const bf* __restrict__ A,
                                              const bf* __restrict__ Bt,
                                              float* __restrict__ Cf,
                                              const int* __restrict__ masks,
                                              bf* __restrict__ Qn,
                                              bf* __restrict__ Kn,
                                              bf* __restrict__ Vt,
                                              int nx, int N, int K) {
    constexpr int MF = BM / 32;          // M fragments per wave
    constexpr int RA = BM / 64;          // A staging rounds (glds16/thread)
    constexpr int RB = BN / 64;
    __shared__ __align__(16) bf Asm[3][BM * 32];
    __shared__ __align__(16) bf Bsm[3][BN * 32];
    const int tid = threadIdx.x;
    const int w = tid >> 6, lane = tid & 63, g = lane >> 4, rl = lane & 15;
    // XCD-chunked bijective swizzle (T1): gridDim.x % 8 == 0
    const int cpx = gridDim.x >> 3;
    const int swz = (blockIdx.x & 7) * cpx + (blockIdx.x >> 3);
    const int m0 = (swz / nx) * BM, n0 = (swz % nx) * BN;
    const int wr = (w >> 1) * (MF * 16), wc = (w & 1) * 64;
    const int lrow = lane >> 2, lseg = lane & 3;
    // pre-swizzled staging source seg (involution with the read XOR)
    const int xseg = lseg ^ ((lrow >> 1) & 3);

    f32x4 acc[MF][4] = {};
    const bf* Ap = A + (size_t)m0 * K;
    const bf* Bp = Bt + (size_t)n0 * K;

    auto stage = [&](int bi, int k0) {
#pragma unroll
        for (int u = 0; u < RA; ++u)
            glds16(Ap + (size_t)(u * 64 + w * 16 + lrow) * K + k0 + xseg * 8,
                   &Asm[bi][(u * 64 + w * 16) * 32]);
#pragma unroll
        for (int u = 0; u < RB; ++u)
            glds16(Bp + (size_t)(u * 64 + w * 16 + lrow) * K + k0 + xseg * 8,
                   &Bsm[bi][(u * 64 + w * 16) * 32]);
    };

    const int T = K >> 5;
    stage(0, 0);
    stage(1, 32);
    int cur = 0, nxt = 2;
    for (int t = 0; t < T; ++t) {
        __builtin_amdgcn_sched_barrier(0);
        if (t < T - 1) {
            if constexpr (RA + RB == 4) VMCNT(4); else VMCNT(3);
        } else {
            VMCNT(0);
        }
        __builtin_amdgcn_s_barrier();     // raw: staged loads stay in flight
        __builtin_amdgcn_sched_barrier(0);
        if (t + 2 < T) stage(nxt, (t + 2) * 32);

        const bf* Ab = Asm[cur];
        const bf* Bb = Bsm[cur];
        bf16x8 af[MF], bfr[4];
#pragma unroll
        for (int m = 0; m < MF; ++m) {
            const int row = wr + m * 16 + rl;
            af[m] = __builtin_bit_cast(bf16x8,
                *(const int4*)&Ab[row * 32 + (g ^ ((row >> 1) & 3)) * 8]);
        }
#pragma unroll
        for (int n = 0; n < 4; ++n) {
            const int row = wc + n * 16 + rl;
            bfr[n] = __builtin_bit_cast(bf16x8,
                *(const int4*)&Bb[row * 32 + (g ^ ((row >> 1) & 3)) * 8]);
        }
        __builtin_amdgcn_s_setprio(1);
#pragma unroll
        for (int m = 0; m < MF; ++m)
#pragma unroll
            for (int n = 0; n < 4; ++n)
                acc[m][n] = mfma16(af[m], bfr[n], acc[m][n]);
        __builtin_amdgcn_s_setprio(0);

        cur = (cur == 2) ? 0 : cur + 1;
        nxt = (nxt == 2) ? 0 : nxt + 1;
    }

    if constexpr (MODE == 0) {
#pragma unroll
        for (int m = 0; m < MF; ++m)
#pragma unroll
            for (int n = 0; n < 4; ++n)
#pragma unroll
                for (int ri = 0; ri < 4; ++ri)
                    Cf[(size_t)(m0 + wr + m * 16 + g * 4 + ri) * N + n0 + wc + n * 16 + rl] =
                        acc[m][n][ri];
    } else {
        const int ncol0 = n0 + wc;   // wave's 64-col base == one head slice
        if (ncol0 < 2048) {
            bf* dst = (ncol0 < 1024) ? Qn : Kn;
            const int h2 = (ncol0 >> 6) & 15;
#pragma unroll
            for (int m = 0; m < MF; ++m) {
#pragma unroll
                for (int ri = 0; ri < 4; ++ri) {
                    const int row = m0 + wr + m * 16 + g * 4 + ri;   // b*S+s
                    float ss = 0.f;
#pragma unroll
                    for (int n = 0; n < 4; ++n) ss += acc[m][n][ri] * acc[m][n][ri];
#pragma unroll
                    for (int d = 1; d < 16; d <<= 1) ss += __shfl_xor(ss, d, 64);
                    const float sc = rsqrtf(ss) * (masks[row] ? 1.0f : 0.0f);
                    const int b = row >> 11, s = row & 2047;
                    const size_t base = ((size_t)(b * HH + h2) * SS + s) * 64;
#pragma unroll
                    for (int n = 0; n < 4; ++n)
                        dst[base + n * 16 + rl] = __float2bfloat16(acc[m][n][ri] * sc);
                }
            }
        } else {
            // fused V transpose: Vt[(b*H+h)*64 + d][s], packed 4-bf16 writes
            const int h2 = (ncol0 - 2048) >> 6;
            const int b = (m0 + wr) >> 11;
            const int sb = ((m0 + wr) & 2047) + g * 4;
#pragma unroll
            for (int m = 0; m < MF; ++m)
#pragma unroll
                for (int n = 0; n < 4; ++n) {
                    const int d = n * 16 + rl;
                    bf t4[4];
#pragma unroll
                    for (int ri = 0; ri < 4; ++ri) t4[ri] = __float2bfloat16(acc[m][n][ri]);
                    *(uint2*)&Vt[((size_t)(b * HH + h2) * 64 + d) * SS + sb + m * 16] =
                        *(uint2*)t4;
                }
        }
    }
}

// ---------------------------------------------------------------
// Attention, 32x32 MFMA + in-register P (T12), q-tile 64, 1024 blocks (LPT).
// 4 waves = (q-half qh) x (k-parity kp). 3-buffer K/V pipeline with counted
// vmcnt BEFORE the barrier (VMCNT(4) waits own stage(t); barrier => all
// waves' tile-t chunks landed; stage(t+2) issued after barrier into the
// buffer last read at t-1). No vmcnt(0) drain in the main loop.
// Partial O's (k-parity) summed via one-time LDS reduce (no softmax).
__global__ __launch_bounds__(256) void k_attn(const bf* __restrict__ Qn,  // [B*H,S,64]
                                              const bf* __restrict__ Kn,  // [B*H,S,64]
                                              const bf* __restrict__ Vt,  // [B*H,64,S]
                                              bf* __restrict__ Ctx) {     // [B*S, D]
    __shared__ __align__(16) bf Ksm[3][64 * 64];  // [kv][d], 24KB
    __shared__ __align__(16) bf Vsm[3][64 * 64];  // [d][kv], 24KB

    const int idx = blockIdx.x;
    const int qt = 31 - (idx >> 5);       // 0..31, largest-first (LPT)
    const int by = idx & 31;              // b*H + h
    const int b = by >> 4, h = by & 15;
    const int tid = threadIdx.x;
    const int w = tid >> 6, lane = tid & 63;
    const int l31 = lane & 31, hl = lane >> 5;
    const int qh = w >> 1;                // q-half: rows qt*64+qh*32 ..+32
    const int kp = w & 1;                 // k-parity: handles pt == kp
    const int qw = qt * 64 + qh * 32;
    const int qg = qw + l31;

    const bf* Qp = Qn + (size_t)by * SS * 64;
    const bf* Kp = Kn + (size_t)by * SS * 64;
    const bf* Vp = Vt + (size_t)by * 64 * SS;

    // hoisted Q (B-operand): col=q=l31, d = st*16 + hl*8 + 0..7
    bf16x8 aqs[4];
#pragma unroll
    for (int st = 0; st < 4; ++st)
        aqs[st] = __builtin_bit_cast(bf16x8,
            *(const int4*)(Qp + (size_t)(qw + l31) * 64 + st * 16 + hl * 8));

    // staging: chunk c = 8 rows x 128B; pre-swizzled source slot
    const int srow = lane >> 3;
    const int sblk = (lane & 7) ^ srow;

    auto stage = [&](int buf, int k0) {
#pragma unroll
        for (int u = 0; u < 2; ++u) {
            const int c = w * 2 + u;
            const int row = c * 8 + srow;
            glds16(Kp + (size_t)(k0 + row) * 64 + sblk * 8, &Ksm[buf][c * 512]);
            glds16(Vp + (size_t)row * SS + k0 + sblk * 8, &Vsm[buf][c * 512]);
        }
    };

    f32x16 accd[2] = {};

    stage(0, 0);
    stage(1, 64);
    int cur = 0, nxt = 2;
    for (int t = 0; t <= qt; ++t) {
        __builtin_amdgcn_sched_barrier(0);
        if (t < qt) { VMCNT(4); } else { VMCNT(0); }
        __builtin_amdgcn_s_barrier();     // all waves' tile-t chunks landed
        __builtin_amdgcn_sched_barrier(0);
        if (t + 2 <= qt) stage(nxt, (t + 2) * 64);

        const int kbase = t * 64 + kp * 32;
        if (kbase <= qw + 31) {
            // ---- QK^T (swapped): D[row=k][col=q]
            f32x16 pc = {};
            __builtin_amdgcn_s_setprio(1);
#pragma unroll
            for (int st = 0; st < 4; ++st) {
                const int r = kp * 32 + l31;
                bf16x8 ak = __builtin_bit_cast(bf16x8,
                    *(const int4*)&Ksm[cur][r * 64 + (((2 * st + hl) ^ (r & 7)) << 3)]);
                pc = mfma32(ak, aqs[st], pc);
            }
            __builtin_amdgcn_s_setprio(0);
            // ---- relu + causal (elementwise only near diagonal)
            const bool dg = (kbase + 31 > qw);
            float pv[16];
#pragma unroll
            for (int m2 = 0; m2 < 16; ++m2) {
                float v = fmaxf(pc[m2], 0.0f);
                if (dg) {
                    const int kg = kbase + (m2 & 3) + 8 * (m2 >> 2) + 4 * hl;
                    if (kg > qg) v = 0.0f;
                }
                pv[m2] = v;
            }
            // ---- pack to bf16 pairs + permlane swaps -> PV A-frags (no LDS)
            unsigned P[8];
#pragma unroll
            for (int m2 = 0; m2 < 8; ++m2) P[m2] = cvt_pk_bf16(pv[2 * m2], pv[2 * m2 + 1]);
            pl32swap(P[0], P[2]);
            pl32swap(P[1], P[3]);
            pl32swap(P[4], P[6]);
            pl32swap(P[5], P[7]);
            // ---- PV: D[row=q][col=d]
            __builtin_amdgcn_s_setprio(1);
#pragma unroll
            for (int s = 0; s < 2; ++s) {
                uint4 pw = {P[4 * s + 0], P[4 * s + 1], P[4 * s + 2], P[4 * s + 3]};
                bf16x8 pa = __builtin_bit_cast(bf16x8, pw);
#pragma unroll
                for (int dt = 0; dt < 2; ++dt) {
                    const int d = dt * 32 + l31;
                    const int slot = kp * 4 + s * 2 + hl;
                    bf16x8 bv = __builtin_bit_cast(bf16x8,
                        *(const int4*)&Vsm[cur][d * 64 + ((slot ^ (d & 7)) << 3)]);
                    accd[dt] = mfma32(pa, bv, accd[dt]);
                }
            }
            __builtin_amdgcn_s_setprio(0);
        }

        cur = (cur == 2) ? 0 : cur + 1;
        nxt = (nxt == 2) ? 0 : nxt + 1;
    }

    // ---- cross-wave (k-parity) reduce via LDS, then kp==0 writes Ctx
    __syncthreads();                      // all tile reads done before reuse
    float* red = (float*)&Ksm[0][0];      // 16KB: 2 q-halves x 8KB
    if (kp == 1) {
#pragma unroll
        for (int dt = 0; dt < 2; ++dt)
#pragma unroll
            for (int m2 = 0; m2 < 16; ++m2)
                red[qh * 2048 + (dt * 16 + m2) * 64 + lane] = accd[dt][m2];
    }
    __syncthreads();
    if (kp == 0) {
#pragma unroll
        for (int dt = 0; dt < 2; ++dt)
#pragma unroll
            for (int m2 = 0; m2 < 16; ++m2) {
                const float v = accd[dt][m2] + red[qh * 2048 + (dt * 16 + m2) * 64 + lane];
                const int q = qw + (m2 & 3) + 8 * (m2 >> 2) + 4 * hl;
                const int d = dt * 32 + l31;
                Ctx[(size_t)(b * SS + q) * DD + h * 64 + d] = __float2bfloat16(v);
            }
    }
}

// ---------------------------------------------------------------
extern "C" void kernel_launch(void* const* d_in, const int* in_sizes, int n_in,
                              void* d_out, int out_size, void* d_ws, size_t ws_size,
                              hipStream_t stream) {
    const float* X  = (const float*)d_in[0];
    const int* masks = (const int*)d_in[1];
    const float* Wq = (const float*)d_in[2];
    const float* Wk = (const float*)d_in[3];
    const float* Wv = (const float*)d_in[4];
    const float* Wo = (const float*)d_in[5];
    float* out = (float*)d_out;
    char* ws = (char*)d_ws;

    const size_t MB = 1024 * 1024;
    bf* Xb   = (bf*)(ws);              // 8 MB  [B*S, D]
    bf* Wqkv = (bf*)(ws + 8  * MB);    // 6 MB  [3072, 1024]
    bf* Wob  = (bf*)(ws + 14 * MB);    // 2 MB
    bf* Qn   = (bf*)(ws + 16 * MB);    // 8 MB  [B*H, S, 64]
    bf* Kn   = (bf*)(ws + 24 * MB);
    bf* Vt   = (bf*)(ws + 32 * MB);    // 8 MB  [B*H, 64, S]
    bf* Ctx  = (bf*)(ws + 40 * MB);    // 8 MB  [B*S, D]

    // converts (one launch)
    k_convert<<<8192, 256, 0, stream>>>(X, Wq, Wk, Wv, Wo, Xb, Wqkv, Wob);

    // fused QKV projection + norm/mask epilogue + V-transpose (768 blocks)
    k_gemm<1, 128, 128><<<(ND3 / 128) * (MMR / 128), 256, 0, stream>>>(
        Xb, Wqkv, nullptr, masks, Qn, Kn, Vt, ND3 / 128, ND3, DD);

    // attention
    k_attn<<<1024, 256, 0, stream>>>(Qn, Kn, Vt, Ctx);

    // output projection (64x128 tiles -> 512 blocks, 2/CU)
    k_gemm<0, 64, 128><<<(DD / 128) * (MMR / 64), 256, 0, stream>>>(
        Ctx, Wob, out, nullptr, nullptr, nullptr, nullptr, DD / 128, DD, DD);
}